// Round 1
// baseline (1634.163 us; speedup 1.0000x reference)
//
#include <hip/hip_runtime.h>
#include <hip/hip_bf16.h>
#include <stdint.h>

#define N_TOK 8192
#define DIM   2048
#define FDIM  4096
#define NEXP  8
#define BM    128
#define BN    128
#define BK    32
#define MT_MAX 64           // ceil(8192/128)
#define HROWS_CAP 17408     // 16384 pairs + 8*128 padding

// ---- ws layout (bytes) ----
#define XB_OFF   0ull                      // bf16 x       [8192][2048]  33,554,432
#define HB_OFF   33554432ull               // bf16 h       [17408][4096] 142,606,336
#define PART_OFF 176160768ull              // f32 partial  [2][8192][2048] 134,217,728
#define META_OFF 310378496ull
#define CNT_OFF  (META_OFF)                // int[8]   (64B)
#define EBASE_OFF (META_OFF + 64ull)       // int[8]   (64B)
#define ELIST_OFF (META_OFF + 128ull)      // int[8][8192]   262,144
#define EWTS_OFF  (ELIST_OFF + 262144ull)  // f32[8][8192]   262,144
#define META_END  (EWTS_OFF + 262144ull)   // 310,902,912
#define WB_OFF    310903040ull             // 256-aligned
#define W1B_OFF   (WB_OFF)
#define W3B_OFF   (WB_OFF + 134217728ull)
#define W2B_OFF   (WB_OFF + 268435456ull)
#define WS_FULL   (WB_OFF + 402653184ull)  // 713,556,224

typedef float f32x4 __attribute__((ext_vector_type(4)));
typedef short s16x8 __attribute__((ext_vector_type(8)));

// pack two fp32 -> two bf16 (round-to-nearest, ties up; bias ~2^-17, negligible)
__device__ __forceinline__ uint32_t pkbf(float a, float b) {
  uint32_t ua = __builtin_bit_cast(uint32_t, a) + 0x8000u;
  uint32_t ub = __builtin_bit_cast(uint32_t, b) + 0x8000u;
  return (ua >> 16) | (ub & 0xffff0000u);
}

// async global->LDS, 16B/lane. Global addr is per-lane; LDS addr must be
// wave-uniform base (+ lane*16 applied by HW).
__device__ __forceinline__ void gld16(const void* g, void* l) {
  __builtin_amdgcn_global_load_lds(
      (__attribute__((address_space(1))) void*)g,
      (__attribute__((address_space(3))) void*)l, 16, 0, 0);
}

__global__ void init_k(int* cnt) {
  if (threadIdx.x < NEXP) cnt[threadIdx.x] = 0;
}

// one block (256 thr) per token: logits fp32, top-2, softmax, list build, x->bf16
__global__ void router_k(const float* __restrict__ x, const float* __restrict__ gw,
                         __hip_bfloat16* __restrict__ xb, int* __restrict__ cnt,
                         int* __restrict__ elist, float* __restrict__ ewts) {
  const int n = blockIdx.x;
  const int t = threadIdx.x;
  const float* xr = x + (size_t)n * DIM;
  const float4 v0 = *(const float4*)(xr + t * 8);
  const float4 v1 = *(const float4*)(xr + t * 8 + 4);
  uint4 u;
  u.x = pkbf(v0.x, v0.y); u.y = pkbf(v0.z, v0.w);
  u.z = pkbf(v1.x, v1.y); u.w = pkbf(v1.z, v1.w);
  *(uint4*)(xb + (size_t)n * DIM + t * 8) = u;

  float p[NEXP];
#pragma unroll
  for (int e = 0; e < NEXP; ++e) {
    const float* g = gw + e * DIM + t * 8;
    const float4 g0 = *(const float4*)g;
    const float4 g1 = *(const float4*)(g + 4);
    p[e] = v0.x * g0.x + v0.y * g0.y + v0.z * g0.z + v0.w * g0.w +
           v1.x * g1.x + v1.y * g1.y + v1.z * g1.z + v1.w * g1.w;
  }
#pragma unroll
  for (int off = 32; off >= 1; off >>= 1)
#pragma unroll
    for (int e = 0; e < NEXP; ++e) p[e] += __shfl_xor(p[e], off, 64);

  __shared__ float red[4][NEXP];
  const int lane = t & 63, wv = t >> 6;
  if (lane == 0) {
#pragma unroll
    for (int e = 0; e < NEXP; ++e) red[wv][e] = p[e];
  }
  __syncthreads();
  if (t == 0) {
    float l0 = -1e30f, l1 = -1e30f;
    int e0 = 0, e1 = 0;
#pragma unroll
    for (int e = 0; e < NEXP; ++e) {
      float v = red[0][e] + red[1][e] + red[2][e] + red[3][e];
      if (v > l0) { l1 = l0; e1 = e0; l0 = v; e0 = e; }
      else if (v > l1) { l1 = v; e1 = e; }
    }
    const float ed = expf(l1 - l0);
    const float inv = 1.f / (1.f + ed);
    const float w0 = inv, w1v = ed * inv;
    int s0 = atomicAdd(cnt + e0, 1);
    elist[e0 * N_TOK + s0] = n;            // slot 0
    ewts[e0 * N_TOK + s0] = w0;
    int s1 = atomicAdd(cnt + e1, 1);
    elist[e1 * N_TOK + s1] = (int)((uint32_t)n | 0x80000000u);  // slot 1
    ewts[e1 * N_TOK + s1] = w1v;
  }
}

__global__ void scan_k(const int* __restrict__ cnt, int* __restrict__ ebase) {
  if (threadIdx.x == 0 && blockIdx.x == 0) {
    int b = 0;
    for (int e = 0; e < NEXP; ++e) { ebase[e] = b; b += (cnt[e] + BM - 1) & ~(BM - 1); }
  }
}

__global__ void convert_k(const float* __restrict__ src, __hip_bfloat16* __restrict__ dst,
                          int nchunks) {
  for (int i = blockIdx.x * blockDim.x + threadIdx.x; i < nchunks;
       i += gridDim.x * blockDim.x) {
    const float4 a = *(const float4*)(src + (size_t)i * 8);
    const float4 b = *(const float4*)(src + (size_t)i * 8 + 4);
    uint4 u;
    u.x = pkbf(a.x, a.y); u.y = pkbf(a.z, a.w);
    u.z = pkbf(b.x, b.y); u.w = pkbf(b.z, b.w);
    *(uint4*)(dst + (size_t)i * 8) = u;
  }
}

// fused gate/up grouped GEMM: h = silu(x@w1^T) * (x@w3^T) for routed rows
template <bool PRE>
__global__ __launch_bounds__(256, 2) void moe_up_k(
    const __hip_bfloat16* __restrict__ xb, const float* __restrict__ w1f,
    const float* __restrict__ w3f, const __hip_bfloat16* __restrict__ w1b,
    const __hip_bfloat16* __restrict__ w3b, __hip_bfloat16* __restrict__ hb,
    const int* __restrict__ cnt, const int* __restrict__ ebase,
    const int* __restrict__ elist) {
  const int e = blockIdx.z;
  const int count = cnt[e];
  const int mt = blockIdx.y;
  if (mt * BM >= count) return;
  const int nt = blockIdx.x;

  __shared__ alignas(16) __hip_bfloat16 As[2][BM * BK];
  __shared__ alignas(16) __hip_bfloat16 B1s[2][BN * BK];
  __shared__ alignas(16) __hip_bfloat16 B3s[2][BN * BK];

  const int t = threadIdx.x;
  const int lane = t & 63;
  const int wv = t >> 6;
  const int wr = wv >> 1, wc = wv & 1;
  const int r0 = t >> 2;              // staged row (chunk = (row, kc))
  const int kc = (t & 3) * 8;         // element offset within BK

  const int* lst = elist + e * N_TOK;
  int i0 = mt * BM + r0;      if (i0 >= count) i0 = 0;   // clamp pad rows
  int i1 = mt * BM + r0 + 64; if (i1 >= count) i1 = 0;
  const int tok0 = lst[i0] & 0x7fffffff;
  const int tok1 = lst[i1] & 0x7fffffff;
  const __hip_bfloat16* gA0 = xb + (size_t)tok0 * DIM + kc;
  const __hip_bfloat16* gA1 = xb + (size_t)tok1 * DIM + kc;

  const size_t bO0 = ((size_t)e * FDIM + nt * BN + r0) * (size_t)DIM + kc;
  const size_t bO1 = bO0 + 64 * (size_t)DIM;

  char* AsB = (char*)As;
  char* B1sB = (char*)B1s;
  char* B3sB = (char*)B3s;
  const int ldsW = wv * 1024;  // wave-uniform LDS base offset (+lane*16 by HW)

  f32x4 accG[4][4], accU[4][4];
#pragma unroll
  for (int mi = 0; mi < 4; ++mi)
#pragma unroll
    for (int ni = 0; ni < 4; ++ni) {
      accG[mi][ni] = {0.f, 0.f, 0.f, 0.f};
      accU[mi][ni] = {0.f, 0.f, 0.f, 0.f};
    }

  float4 q[8];
  auto stageA = [&](int k0, int b) {
    gld16(gA0 + k0, AsB + b * 8192 + ldsW);
    gld16(gA1 + k0, AsB + b * 8192 + 4096 + ldsW);
  };
  auto stageBpre = [&](int k0, int b) {
    gld16(w1b + bO0 + k0, B1sB + b * 8192 + ldsW);
    gld16(w1b + bO1 + k0, B1sB + b * 8192 + 4096 + ldsW);
    gld16(w3b + bO0 + k0, B3sB + b * 8192 + ldsW);
    gld16(w3b + bO1 + k0, B3sB + b * 8192 + 4096 + ldsW);
  };
  auto loadB = [&](int k0) {  // issue early (T14): latency hides under MFMA
    q[0] = *(const float4*)(w1f + bO0 + k0);
    q[1] = *(const float4*)(w1f + bO0 + k0 + 4);
    q[2] = *(const float4*)(w1f + bO1 + k0);
    q[3] = *(const float4*)(w1f + bO1 + k0 + 4);
    q[4] = *(const float4*)(w3f + bO0 + k0);
    q[5] = *(const float4*)(w3f + bO0 + k0 + 4);
    q[6] = *(const float4*)(w3f + bO1 + k0);
    q[7] = *(const float4*)(w3f + bO1 + k0 + 4);
  };
  auto writeB = [&](int b) {
    uint4 u;
    u.x = pkbf(q[0].x, q[0].y); u.y = pkbf(q[0].z, q[0].w);
    u.z = pkbf(q[1].x, q[1].y); u.w = pkbf(q[1].z, q[1].w);
    *(uint4*)(B1sB + b * 8192 + t * 16) = u;
    u.x = pkbf(q[2].x, q[2].y); u.y = pkbf(q[2].z, q[2].w);
    u.z = pkbf(q[3].x, q[3].y); u.w = pkbf(q[3].z, q[3].w);
    *(uint4*)(B1sB + b * 8192 + 4096 + t * 16) = u;
    u.x = pkbf(q[4].x, q[4].y); u.y = pkbf(q[4].z, q[4].w);
    u.z = pkbf(q[5].x, q[5].y); u.w = pkbf(q[5].z, q[5].w);
    *(uint4*)(B3sB + b * 8192 + t * 16) = u;
    u.x = pkbf(q[6].x, q[6].y); u.y = pkbf(q[6].z, q[6].w);
    u.z = pkbf(q[7].x, q[7].y); u.w = pkbf(q[7].z, q[7].w);
    *(uint4*)(B3sB + b * 8192 + 4096 + t * 16) = u;
  };
  auto compute = [&](int b) {
    const __hip_bfloat16* Ab = (const __hip_bfloat16*)(AsB + b * 8192);
    const __hip_bfloat16* B1b = (const __hip_bfloat16*)(B1sB + b * 8192);
    const __hip_bfloat16* B3b = (const __hip_bfloat16*)(B3sB + b * 8192);
    const int fr = lane & 15;
    const int fk = (lane >> 4) * 8;
    s16x8 af[4], b1f[4], b3f[4];
#pragma unroll
    for (int mi = 0; mi < 4; ++mi)
      af[mi] = *(const s16x8*)(Ab + (wr * 64 + mi * 16 + fr) * BK + fk);
#pragma unroll
    for (int ni = 0; ni < 4; ++ni) {
      b1f[ni] = *(const s16x8*)(B1b + (wc * 64 + ni * 16 + fr) * BK + fk);
      b3f[ni] = *(const s16x8*)(B3b + (wc * 64 + ni * 16 + fr) * BK + fk);
    }
#pragma unroll
    for (int mi = 0; mi < 4; ++mi)
#pragma unroll
      for (int ni = 0; ni < 4; ++ni) {
        accG[mi][ni] = __builtin_amdgcn_mfma_f32_16x16x32_bf16(
            af[mi], b1f[ni], accG[mi][ni], 0, 0, 0);
        accU[mi][ni] = __builtin_amdgcn_mfma_f32_16x16x32_bf16(
            af[mi], b3f[ni], accU[mi][ni], 0, 0, 0);
      }
  };

  if constexpr (PRE) {
    stageA(0, 0); stageBpre(0, 0);
  } else {
    loadB(0); stageA(0, 0); writeB(0);
  }
  __syncthreads();

  int b = 0;
  for (int kt = 0; kt < DIM / BK; ++kt) {
    const int nk = (kt + 1) * BK;
    if constexpr (PRE) {
      if (nk < DIM) { stageA(nk, b ^ 1); stageBpre(nk, b ^ 1); }
      compute(b);
    } else {
      if (nk < DIM) { loadB(nk); stageA(nk, b ^ 1); }
      compute(b);
      if (nk < DIM) writeB(b ^ 1);
    }
    __syncthreads();
    b ^= 1;
  }

  const size_t hrow0 = (size_t)ebase[e] + (size_t)(mt * BM);
  const int crow = (lane >> 4) * 4;
  const int ccol = lane & 15;
#pragma unroll
  for (int mi = 0; mi < 4; ++mi)
#pragma unroll
    for (int ni = 0; ni < 4; ++ni) {
      const int cb = nt * BN + wc * 64 + ni * 16 + ccol;
#pragma unroll
      for (int j = 0; j < 4; ++j) {
        const int r = wr * 64 + mi * 16 + crow + j;
        const float g = accG[mi][ni][j];
        const float uu = accU[mi][ni][j];
        const float h = g / (1.f + __expf(-g)) * uu;   // silu(g)*u
        hb[(hrow0 + r) * (size_t)FDIM + cb] = __float2bfloat16(h);
      }
    }
}

// down grouped GEMM: partial[slot][tok] = we * (h @ w2^T)
template <bool PRE>
__global__ __launch_bounds__(256, 2) void moe_down_k(
    const __hip_bfloat16* __restrict__ hb, const float* __restrict__ w2f,
    const __hip_bfloat16* __restrict__ w2b, float* __restrict__ part,
    const int* __restrict__ cnt, const int* __restrict__ ebase,
    const int* __restrict__ elist, const float* __restrict__ ewts) {
  const int e = blockIdx.z;
  const int count = cnt[e];
  const int mt = blockIdx.y;
  if (mt * BM >= count) return;
  const int nt = blockIdx.x;

  __shared__ alignas(16) __hip_bfloat16 As[2][BM * BK];
  __shared__ alignas(16) __hip_bfloat16 Bs[2][BN * BK];

  const int t = threadIdx.x;
  const int lane = t & 63;
  const int wv = t >> 6;
  const int wr = wv >> 1, wc = wv & 1;
  const int r0 = t >> 2;
  const int kc = (t & 3) * 8;

  const size_t hrow0 = (size_t)ebase[e] + (size_t)(mt * BM);
  const __hip_bfloat16* gA0 = hb + (hrow0 + r0) * (size_t)FDIM + kc;
  const __hip_bfloat16* gA1 = gA0 + 64 * (size_t)FDIM;
  const size_t bO0 = ((size_t)e * DIM + nt * BN + r0) * (size_t)FDIM + kc;
  const size_t bO1 = bO0 + 64 * (size_t)FDIM;

  char* AsB = (char*)As;
  char* BsB = (char*)Bs;
  const int ldsW = wv * 1024;

  f32x4 acc[4][4];
#pragma unroll
  for (int mi = 0; mi < 4; ++mi)
#pragma unroll
    for (int ni = 0; ni < 4; ++ni) acc[mi][ni] = {0.f, 0.f, 0.f, 0.f};

  float4 q[4];
  auto stageA = [&](int k0, int b) {
    gld16(gA0 + k0, AsB + b * 8192 + ldsW);
    gld16(gA1 + k0, AsB + b * 8192 + 4096 + ldsW);
  };
  auto stageBpre = [&](int k0, int b) {
    gld16(w2b + bO0 + k0, BsB + b * 8192 + ldsW);
    gld16(w2b + bO1 + k0, BsB + b * 8192 + 4096 + ldsW);
  };
  auto loadB = [&](int k0) {
    q[0] = *(const float4*)(w2f + bO0 + k0);
    q[1] = *(const float4*)(w2f + bO0 + k0 + 4);
    q[2] = *(const float4*)(w2f + bO1 + k0);
    q[3] = *(const float4*)(w2f + bO1 + k0 + 4);
  };
  auto writeB = [&](int b) {
    uint4 u;
    u.x = pkbf(q[0].x, q[0].y); u.y = pkbf(q[0].z, q[0].w);
    u.z = pkbf(q[1].x, q[1].y); u.w = pkbf(q[1].z, q[1].w);
    *(uint4*)(BsB + b * 8192 + t * 16) = u;
    u.x = pkbf(q[2].x, q[2].y); u.y = pkbf(q[2].z, q[2].w);
    u.z = pkbf(q[3].x, q[3].y); u.w = pkbf(q[3].z, q[3].w);
    *(uint4*)(BsB + b * 8192 + 4096 + t * 16) = u;
  };
  auto compute = [&](int b) {
    const __hip_bfloat16* Ab = (const __hip_bfloat16*)(AsB + b * 8192);
    const __hip_bfloat16* Bb = (const __hip_bfloat16*)(BsB + b * 8192);
    const int fr = lane & 15;
    const int fk = (lane >> 4) * 8;
    s16x8 af[4], bf[4];
#pragma unroll
    for (int mi = 0; mi < 4; ++mi)
      af[mi] = *(const s16x8*)(Ab + (wr * 64 + mi * 16 + fr) * BK + fk);
#pragma unroll
    for (int ni = 0; ni < 4; ++ni)
      bf[ni] = *(const s16x8*)(Bb + (wc * 64 + ni * 16 + fr) * BK + fk);
#pragma unroll
    for (int mi = 0; mi < 4; ++mi)
#pragma unroll
      for (int ni = 0; ni < 4; ++ni)
        acc[mi][ni] = __builtin_amdgcn_mfma_f32_16x16x32_bf16(
            af[mi], bf[ni], acc[mi][ni], 0, 0, 0);
  };

  if constexpr (PRE) {
    stageA(0, 0); stageBpre(0, 0);
  } else {
    loadB(0); stageA(0, 0); writeB(0);
  }
  __syncthreads();

  int b = 0;
  for (int kt = 0; kt < FDIM / BK; ++kt) {
    const int nk = (kt + 1) * BK;
    if constexpr (PRE) {
      if (nk < FDIM) { stageA(nk, b ^ 1); stageBpre(nk, b ^ 1); }
      compute(b);
    } else {
      if (nk < FDIM) { loadB(nk); stageA(nk, b ^ 1); }
      compute(b);
      if (nk < FDIM) writeB(b ^ 1);
    }
    __syncthreads();
    b ^= 1;
  }

  const int* lst = elist + e * N_TOK;
  const float* wts = ewts + e * N_TOK;
  const int crow = (lane >> 4) * 4;
  const int ccol = lane & 15;
#pragma unroll
  for (int mi = 0; mi < 4; ++mi)
#pragma unroll
    for (int j = 0; j < 4; ++j) {
      const int i = mt * BM + wr * 64 + mi * 16 + crow + j;
      if (i < count) {
        const uint32_t info = (uint32_t)lst[i];
        const int tok = (int)(info & 0x7fffffffu);
        const int slot = (int)(info >> 31);
        const float wt = wts[i];
        float* prow = part + ((size_t)slot * N_TOK + tok) * DIM;
#pragma unroll
        for (int ni = 0; ni < 4; ++ni) {
          const int cb = nt * BN + wc * 64 + ni * 16 + ccol;
          prow[cb] = wt * acc[mi][ni][j];
        }
      }
    }
}

__global__ void combine_k(const float* __restrict__ part, float* __restrict__ out) {
  const size_t i4 = (size_t)blockIdx.x * 256 + threadIdx.x;
  const size_t idx = i4 * 4;
  const float4 a = *(const float4*)(part + idx);
  const float4 b = *(const float4*)(part + (size_t)N_TOK * DIM + idx);
  float4 o;
  o.x = a.x + b.x; o.y = a.y + b.y; o.z = a.z + b.z; o.w = a.w + b.w;
  *(float4*)(out + idx) = o;
}

extern "C" void kernel_launch(void* const* d_in, const int* in_sizes, int n_in,
                              void* d_out, int out_size, void* d_ws, size_t ws_size,
                              hipStream_t stream) {
  const float* stm = (const float*)d_in[0];
  const float* gw = (const float*)d_in[1];
  const float* w1 = (const float*)d_in[2];
  const float* w2 = (const float*)d_in[3];
  const float* w3 = (const float*)d_in[4];
  float* out = (float*)d_out;
  char* ws = (char*)d_ws;

  __hip_bfloat16* xb = (__hip_bfloat16*)(ws + XB_OFF);
  __hip_bfloat16* hb = (__hip_bfloat16*)(ws + HB_OFF);
  float* part = (float*)(ws + PART_OFF);
  int* cnt = (int*)(ws + CNT_OFF);
  int* ebase = (int*)(ws + EBASE_OFF);
  int* elist = (int*)(ws + ELIST_OFF);
  float* ewts = (float*)(ws + EWTS_OFF);
  __hip_bfloat16* w1b = (__hip_bfloat16*)(ws + W1B_OFF);
  __hip_bfloat16* w3b = (__hip_bfloat16*)(ws + W3B_OFF);
  __hip_bfloat16* w2b = (__hip_bfloat16*)(ws + W2B_OFF);

  const bool pre = (ws_size >= WS_FULL);

  init_k<<<1, 64, 0, stream>>>(cnt);
  router_k<<<N_TOK, 256, 0, stream>>>(stm, gw, xb, cnt, elist, ewts);
  scan_k<<<1, 64, 0, stream>>>(cnt, ebase);

  const dim3 gUp(FDIM / BN, MT_MAX, NEXP);
  const dim3 gDn(DIM / BN, MT_MAX, NEXP);
  const int wchunks = NEXP * FDIM * DIM / 8;  // 8,388,608 per matrix

  if (pre) {
    convert_k<<<8192, 256, 0, stream>>>(w1, w1b, wchunks);
    convert_k<<<8192, 256, 0, stream>>>(w3, w3b, wchunks);
    convert_k<<<8192, 256, 0, stream>>>(w2, w2b, wchunks);
    moe_up_k<true><<<gUp, 256, 0, stream>>>(xb, w1, w3, w1b, w3b, hb, cnt, ebase, elist);
    moe_down_k<true><<<gDn, 256, 0, stream>>>(hb, w2, w2b, part, cnt, ebase, elist, ewts);
  } else {
    moe_up_k<false><<<gUp, 256, 0, stream>>>(xb, w1, w3, w1b, w3b, hb, cnt, ebase, elist);
    moe_down_k<false><<<gDn, 256, 0, stream>>>(hb, w2, w2b, part, cnt, ebase, elist, ewts);
  }

  combine_k<<<N_TOK * DIM / 1024, 256, 0, stream>>>(part, out);
}